// Round 6
// baseline (1727.237 us; speedup 1.0000x reference)
//
#include <hip/hip_runtime.h>

#define IN_DIM 128
#define HID 64
#define ODIM 40
#define BSH 7
#define BSZ 128        // nodes per bucket
#define NBMAX 1024     // max buckets (n <= 131072)

// ================= bucket count (+ degree) =================
// LDS histogram of dst>>7 merged into global bcnt; per-node degree via device atomics.

__global__ __launch_bounds__(256) void k_bcount(const int* __restrict__ dst,
                                                int* __restrict__ deg,
                                                int* __restrict__ bcnt, int e, int nb) {
    __shared__ int hist[NBMAX];
    const int t = threadIdx.x;
    for (int i = t; i < nb; i += 256) hist[i] = 0;
    __syncthreads();
    for (int i = blockIdx.x * 256 + t; i < e; i += gridDim.x * 256) {
        int d = dst[i];
        atomicAdd(&deg[d], 1);
        atomicAdd(&hist[d >> BSH], 1);
    }
    __syncthreads();
    for (int i = t; i < nb; i += 256) {
        int v = hist[i];
        if (v) atomicAdd(&bcnt[i], v);
    }
}

__global__ __launch_bounds__(256) void k_dinv(const int* __restrict__ deg,
                                              float* __restrict__ dinv, int n) {
    int i = blockIdx.x * 256 + threadIdx.x;
    if (i < n) dinv[i] = rsqrtf((float)(deg[i] + 1));  // +1 self loop; always > 0
}

// single block, 1024 threads: exclusive scan of bcnt[nb] -> bbase
__global__ __launch_bounds__(1024) void k_bscan(const int* __restrict__ bcnt,
                                                int* __restrict__ bbase, int nb) {
    __shared__ int tmp[NBMAX];
    const int tid = threadIdx.x;
    int v = (tid < nb) ? bcnt[tid] : 0;
    tmp[tid] = v;
    __syncthreads();
    for (int off = 1; off < NBMAX; off <<= 1) {
        int t = (tid >= off) ? tmp[tid - off] : 0;
        __syncthreads();
        tmp[tid] += t;
        __syncthreads();
    }
    if (tid < nb) bbase[tid] = tmp[tid] - v;  // exclusive
}

// scatter: edge -> its dst-bucket region, packed as src | (local_dst << 20)
// (src < 2^20; local_dst < 128). Writes land bucket-sequential -> L2-friendly.
__global__ __launch_bounds__(256) void k_bscatter(const int* __restrict__ src,
                                                  const int* __restrict__ dst,
                                                  const int* __restrict__ bbase,
                                                  int* __restrict__ bcur,
                                                  int* __restrict__ ebuf, int e) {
    for (int i = blockIdx.x * 256 + threadIdx.x; i < e; i += gridDim.x * 256) {
        int s = src[i], d = dst[i];
        int b = d >> BSH;
        int p = bbase[b] + atomicAdd(&bcur[b], 1);
        ebuf[p] = s | ((d & (BSZ - 1)) << 20);
    }
}

// ================= GEMM1: P1 = (x @ W1) * dinv[row]  [N,128]x[128,64] =================

__global__ __launch_bounds__(256) void k_gemm1(const float* __restrict__ x,
                                               const float* __restrict__ W,
                                               const float* __restrict__ dinv,
                                               float* __restrict__ P, int n) {
    __shared__ float Ws[IN_DIM * HID];  // 32 KB
    const int t = threadIdx.x;
    {
        const float4* W4 = (const float4*)W;
        float4* Ws4 = (float4*)Ws;
#pragma unroll
        for (int i = 0; i < 8; ++i) Ws4[t + 256 * i] = W4[t + 256 * i];
    }
    __syncthreads();

    const int row0 = blockIdx.x * 64;
    const int ty = t >> 4, tx = t & 15;  // 4 rows x 4 cols per thread
    float acc[4][4];
#pragma unroll
    for (int i = 0; i < 4; ++i)
#pragma unroll
        for (int j = 0; j < 4; ++j) acc[i][j] = 0.f;

    const float4* x4 = (const float4*)x;
    int gr[4];
#pragma unroll
    for (int i = 0; i < 4; ++i) {
        int r = row0 + ty * 4 + i;
        gr[i] = r < n ? r : (n - 1);  // clamp for safe load; store is guarded
    }

#pragma unroll 2
    for (int k = 0; k < IN_DIM; k += 4) {
        float aa[4][4];
#pragma unroll
        for (int i = 0; i < 4; ++i) {
            float4 av = x4[(size_t)gr[i] * 32 + (k >> 2)];
            aa[i][0] = av.x; aa[i][1] = av.y; aa[i][2] = av.z; aa[i][3] = av.w;
        }
#pragma unroll
        for (int q = 0; q < 4; ++q) {
            float4 bv = *(const float4*)&Ws[(k + q) * HID + tx * 4];
#pragma unroll
            for (int i = 0; i < 4; ++i) {
                acc[i][0] = fmaf(aa[i][q], bv.x, acc[i][0]);
                acc[i][1] = fmaf(aa[i][q], bv.y, acc[i][1]);
                acc[i][2] = fmaf(aa[i][q], bv.z, acc[i][2]);
                acc[i][3] = fmaf(aa[i][q], bv.w, acc[i][3]);
            }
        }
    }

#pragma unroll
    for (int i = 0; i < 4; ++i) {
        int r = row0 + ty * 4 + i;
        if (r < n) {
            float s = dinv[r];
            float4 o = make_float4(acc[i][0] * s, acc[i][1] * s, acc[i][2] * s, acc[i][3] * s);
            *(float4*)&P[(size_t)r * HID + tx * 4] = o;
        }
    }
}

// ================= GEMM2: P2 = (h @ W2) * dinv[row]  [N,64]x[64,40] =================

__global__ __launch_bounds__(256) void k_gemm2(const float* __restrict__ h,
                                               const float* __restrict__ W,
                                               const float* __restrict__ dinv,
                                               float* __restrict__ P, int n) {
    __shared__ float Ws[HID * 48];  // padded cols, 12 KB
    const int t = threadIdx.x;
#pragma unroll
    for (int i = 0; i < 12; ++i) {
        int idx = t + 256 * i;
        int r = idx / 48, c = idx - r * 48;
        Ws[idx] = (c < ODIM) ? W[r * ODIM + c] : 0.f;
    }
    __syncthreads();

    const int row0 = blockIdx.x * 64;
    const int ty = t >> 4, tx = t & 15;  // 4 rows x 3 cols
    float acc[4][3];
#pragma unroll
    for (int i = 0; i < 4; ++i)
#pragma unroll
        for (int j = 0; j < 3; ++j) acc[i][j] = 0.f;

    const float4* h4 = (const float4*)h;
    int gr[4];
#pragma unroll
    for (int i = 0; i < 4; ++i) {
        int r = row0 + ty * 4 + i;
        gr[i] = r < n ? r : (n - 1);
    }

#pragma unroll 2
    for (int k = 0; k < HID; k += 4) {
        float aa[4][4];
#pragma unroll
        for (int i = 0; i < 4; ++i) {
            float4 av = h4[(size_t)gr[i] * 16 + (k >> 2)];
            aa[i][0] = av.x; aa[i][1] = av.y; aa[i][2] = av.z; aa[i][3] = av.w;
        }
#pragma unroll
        for (int q = 0; q < 4; ++q) {
            const float* wr = &Ws[(k + q) * 48 + tx * 3];
            float b0 = wr[0], b1v = wr[1], b2v = wr[2];
#pragma unroll
            for (int i = 0; i < 4; ++i) {
                acc[i][0] = fmaf(aa[i][q], b0, acc[i][0]);
                acc[i][1] = fmaf(aa[i][q], b1v, acc[i][1]);
                acc[i][2] = fmaf(aa[i][q], b2v, acc[i][2]);
            }
        }
    }

#pragma unroll
    for (int i = 0; i < 4; ++i) {
        int r = row0 + ty * 4 + i;
        if (r < n) {
            float s = dinv[r];
#pragma unroll
            for (int j = 0; j < 3; ++j) {
                int c = tx * 3 + j;
                if (c < ODIM) P[(size_t)r * ODIM + c] = acc[i][j] * s;
            }
        }
    }
}

// ================= bucketed aggregation + finalize =================
// One block per 128-node bucket; LDS accumulator [128][feats].
// Waves gather P-rows (float4/lane, 4 edges/wave, unroll 4 -> 16 gathers in flight)
// and ds_add_f32 into LDS. Epilogue: h = relu(dinv*(acc+self)+b) fused on writeback.

__global__ __launch_bounds__(256) void k_agg1b(const int* __restrict__ ebuf,
                                               const int* __restrict__ bbase,
                                               const float4* __restrict__ P4,
                                               const float* __restrict__ dinv,
                                               const float* __restrict__ bias,
                                               float4* __restrict__ h4, int n, int nb, int e) {
    __shared__ float accs[BSZ * HID];  // 32 KB
    float4* acc4 = (float4*)accs;
    const int t = threadIdx.x;
    const int b = blockIdx.x;
    const int node0 = b << BSH;
    for (int i = t; i < BSZ * (HID / 4); i += 256) acc4[i] = make_float4(0.f, 0.f, 0.f, 0.f);
    __syncthreads();

    const int beg = bbase[b];
    const int end = (b + 1 < nb) ? bbase[b + 1] : e;
    const int lane = t & 63, w = t >> 6;
    const int grp = lane >> 4, q = lane & 15;  // edge-slot, float4-chunk

    for (int i = beg + w * 16; i < end; i += 64) {
        float4 v[4]; int base[4]; bool val[4];
#pragma unroll
        for (int u = 0; u < 4; ++u) {
            int idx = i + u * 4 + grp;
            val[u] = idx < end;
            if (val[u]) {
                int pk = ebuf[idx];
                int s = pk & 0xFFFFF;
                int dloc = pk >> 20;
                v[u] = P4[(size_t)s * 16 + q];
                base[u] = dloc * HID + q * 4;
            }
        }
#pragma unroll
        for (int u = 0; u < 4; ++u) {
            if (val[u]) {
                atomicAdd(&accs[base[u] + 0], v[u].x);
                atomicAdd(&accs[base[u] + 1], v[u].y);
                atomicAdd(&accs[base[u] + 2], v[u].z);
                atomicAdd(&accs[base[u] + 3], v[u].w);
            }
        }
    }
    __syncthreads();

    for (int i = t; i < BSZ * (HID / 4); i += 256) {
        int local = i >> 4, qq = i & 15;
        int node = node0 + local;
        if (node < n) {
            float4 a = acc4[i];
            float4 self = P4[(size_t)node * 16 + qq];
            float di = dinv[node];
            float4 bb = *(const float4*)&bias[qq * 4];
            float4 r;
            r.x = fmaxf(fmaf(di, a.x + self.x, bb.x), 0.f);
            r.y = fmaxf(fmaf(di, a.y + self.y, bb.y), 0.f);
            r.z = fmaxf(fmaf(di, a.z + self.z, bb.z), 0.f);
            r.w = fmaxf(fmaf(di, a.w + self.w, bb.w), 0.f);
            h4[(size_t)node * 16 + qq] = r;
        }
    }
}

// layer2: 40 feats = 10 float4; 6 edge-slots x 10 chunks = 60 active lanes, unroll 2.
__global__ __launch_bounds__(256) void k_agg2b(const int* __restrict__ ebuf,
                                               const int* __restrict__ bbase,
                                               const float4* __restrict__ P4,
                                               const float* __restrict__ dinv,
                                               const float* __restrict__ bias,
                                               float4* __restrict__ out4, int n, int nb, int e) {
    __shared__ float accs[BSZ * ODIM];  // 20 KB
    float4* acc4 = (float4*)accs;
    const int t = threadIdx.x;
    const int b = blockIdx.x;
    const int node0 = b << BSH;
    for (int i = t; i < BSZ * 10; i += 256) acc4[i] = make_float4(0.f, 0.f, 0.f, 0.f);
    __syncthreads();

    const int beg = bbase[b];
    const int end = (b + 1 < nb) ? bbase[b + 1] : e;
    const int lane = t & 63, w = t >> 6;
    const int grp = lane / 10;          // 0..6 (lanes 60-63 inactive)
    const int q = lane - grp * 10;      // 0..9
    const bool act = lane < 60;

    for (int i = beg + w * 12; i < end; i += 48) {
        float4 v[2]; int base[2]; bool val[2];
#pragma unroll
        for (int u = 0; u < 2; ++u) {
            int idx = i + u * 6 + grp;
            val[u] = act && (idx < end);
            if (val[u]) {
                int pk = ebuf[idx];
                int s = pk & 0xFFFFF;
                int dloc = pk >> 20;
                v[u] = P4[(size_t)s * 10 + q];
                base[u] = dloc * ODIM + q * 4;
            }
        }
#pragma unroll
        for (int u = 0; u < 2; ++u) {
            if (val[u]) {
                atomicAdd(&accs[base[u] + 0], v[u].x);
                atomicAdd(&accs[base[u] + 1], v[u].y);
                atomicAdd(&accs[base[u] + 2], v[u].z);
                atomicAdd(&accs[base[u] + 3], v[u].w);
            }
        }
    }
    __syncthreads();

    for (int i = t; i < BSZ * 10; i += 256) {
        int local = i / 10, qq = i - local * 10;
        int node = node0 + local;
        if (node < n) {
            float4 a = acc4[i];
            float4 self = P4[(size_t)node * 10 + qq];
            float di = dinv[node];
            float4 bb = *(const float4*)&bias[qq * 4];
            float4 r;
            r.x = fmaf(di, a.x + self.x, bb.x);
            r.y = fmaf(di, a.y + self.y, bb.y);
            r.z = fmaf(di, a.z + self.z, bb.z);
            r.w = fmaf(di, a.w + self.w, bb.w);
            out4[(size_t)node * 10 + qq] = r;
        }
    }
}

// ================= launch =================

extern "C" void kernel_launch(void* const* d_in, const int* in_sizes, int n_in,
                              void* d_out, int out_size, void* d_ws, size_t ws_size,
                              hipStream_t stream) {
    const float* x  = (const float*)d_in[0];
    const int*   ei = (const int*)d_in[1];
    const float* W1 = (const float*)d_in[2];
    const float* b1 = (const float*)d_in[3];
    const float* W2 = (const float*)d_in[4];
    const float* b2 = (const float*)d_in[5];

    const int n = in_sizes[0] / IN_DIM;   // 100000
    const int e = in_sizes[1] / 2;        // 1600000
    const int* src = ei;
    const int* dst = ei + e;
    const int nb = (n + BSZ - 1) >> BSH;  // 782

    auto align = [](size_t b) { return (b + 255) & ~(size_t)255; };
    char* ws = (char*)d_ws;
    size_t o = 0;
    int*   deg   = (int*)(ws + o);   o += (size_t)n * 4;      // deg + bcnt + bcur: one memset
    int*   bcnt  = (int*)(ws + o);   o += (size_t)NBMAX * 4;
    int*   bcur  = (int*)(ws + o);   o += (size_t)NBMAX * 4;
    o = align(o);
    float* dinv  = (float*)(ws + o); o += align((size_t)n * 4);
    int*   bbase = (int*)(ws + o);   o += align((size_t)NBMAX * 4);
    int*   ebuf  = (int*)(ws + o);   o += align((size_t)e * 4);          // 6.4 MB
    float* P1    = (float*)(ws + o); o += align((size_t)n * HID * 4);    // 25.6 MB (reused as P2)
    float* h     = (float*)(ws + o); o += align((size_t)n * HID * 4);    // 25.6 MB
    // total ~58.4 MB

    float* out = (float*)d_out;

    hipMemsetAsync(deg, 0, ((size_t)n + 2 * NBMAX) * 4, stream);  // deg + bcnt + bcur

    // ---- bucket build (+deg/dinv) ----
    k_bcount<<<1024, 256, 0, stream>>>(dst, deg, bcnt, e, nb);
    k_dinv<<<(n + 255) / 256, 256, 0, stream>>>(deg, dinv, n);
    k_bscan<<<1, 1024, 0, stream>>>(bcnt, bbase, nb);
    k_bscatter<<<1024, 256, 0, stream>>>(src, dst, bbase, bcur, ebuf, e);

    // ---- layer 1 ----
    k_gemm1<<<(n + 63) / 64, 256, 0, stream>>>(x, W1, dinv, P1, n);
    k_agg1b<<<nb, 256, 0, stream>>>(ebuf, bbase, (const float4*)P1, dinv, b1,
                                    (float4*)h, n, nb, e);

    // ---- layer 2 (P2 reuses P1 buffer) ----
    k_gemm2<<<(n + 63) / 64, 256, 0, stream>>>(h, W2, dinv, P1, n);
    k_agg2b<<<nb, 256, 0, stream>>>(ebuf, bbase, (const float4*)P1, dinv, b2,
                                    (float4*)out, n, nb, e);
}

// Round 8
// 694.155 us; speedup vs baseline: 2.4883x; 2.4883x over previous
//
#include <hip/hip_runtime.h>

#define IN_DIM 128
#define HID 64
#define ODIM 40
#define BSH 7
#define BSZ 128        // nodes per bucket
#define NBMAX 1024     // max buckets (n <= 131072)

// ================= bucket histogram =================

__global__ __launch_bounds__(256) void k_bcount(const int* __restrict__ dst,
                                                int* __restrict__ bcnt, int e, int nb) {
    __shared__ int hist[NBMAX];
    const int t = threadIdx.x;
    for (int i = t; i < nb; i += 256) hist[i] = 0;
    __syncthreads();
    for (int i = blockIdx.x * 256 + t; i < e; i += gridDim.x * 256)
        atomicAdd(&hist[dst[i] >> BSH], 1);
    __syncthreads();
    for (int i = t; i < nb; i += 256) {
        int v = hist[i];
        if (v) atomicAdd(&bcnt[i], v);
    }
}

// single block, 1024 threads: exclusive scan of bcnt[nb] -> bbase; rowptr[n] = e
__global__ __launch_bounds__(1024) void k_bscan(const int* __restrict__ bcnt,
                                                int* __restrict__ bbase,
                                                int* __restrict__ rowptr, int n, int nb, int e) {
    __shared__ int tmp[NBMAX];
    const int tid = threadIdx.x;
    int v = (tid < nb) ? bcnt[tid] : 0;
    tmp[tid] = v;
    __syncthreads();
    for (int off = 1; off < NBMAX; off <<= 1) {
        int t = (tid >= off) ? tmp[tid - off] : 0;
        __syncthreads();
        tmp[tid] += t;
        __syncthreads();
    }
    if (tid < nb) bbase[tid] = tmp[tid] - v;  // exclusive
    if (tid == 0) rowptr[n] = e;
}

// scatter: edge -> dst-bucket region, packed as src | (local_dst << 20)
// (src < 2^20, local_dst < 128). Active write window = 6.4 MB, L2-absorbable.
__global__ __launch_bounds__(256) void k_bscatter(const int* __restrict__ src,
                                                  const int* __restrict__ dst,
                                                  const int* __restrict__ bbase,
                                                  int* __restrict__ bcur,
                                                  int* __restrict__ ebuf, int e) {
    for (int i = blockIdx.x * 256 + threadIdx.x; i < e; i += gridDim.x * 256) {
        int s = src[i], d = dst[i];
        int b = d >> BSH;
        int p = bbase[b] + atomicAdd(&bcur[b], 1);
        ebuf[p] = s | ((d & (BSZ - 1)) << 20);
    }
}

// per-bucket counting sort: ebuf (bucket-grouped) -> esrc (CSR-ordered, same region)
// also emits rowptr[node] and dinv[node]. Two sequential passes over the bucket,
// no capacity limit (nothing staged in LDS but 128 counters).
__global__ __launch_bounds__(256) void k_bsort(const int* __restrict__ ebuf,
                                               const int* __restrict__ bbase,
                                               int* __restrict__ esrc,
                                               int* __restrict__ rowptr,
                                               float* __restrict__ dinv,
                                               int n, int nb, int e) {
    __shared__ int hist[BSZ];
    __shared__ int sc[BSZ];
    __shared__ int hoff[BSZ];
    const int t = threadIdx.x;
    const int b = blockIdx.x;
    const int node0 = b << BSH;
    if (t < BSZ) hist[t] = 0;
    __syncthreads();
    const int beg = bbase[b];
    const int end = (b + 1 < nb) ? bbase[b + 1] : e;
    for (int i = beg + t; i < end; i += 256)
        atomicAdd(&hist[ebuf[i] >> 20], 1);
    __syncthreads();
    int v = (t < BSZ) ? hist[t] : 0;
    if (t < BSZ) sc[t] = v;
    __syncthreads();
    for (int off = 1; off < BSZ; off <<= 1) {
        int add = (t < BSZ && t >= off) ? sc[t - off] : 0;
        __syncthreads();
        if (t < BSZ) sc[t] += add;
        __syncthreads();
    }
    if (t < BSZ) {
        int excl = sc[t] - v;
        hoff[t] = excl;  // cursor
        int node = node0 + t;
        if (node < n) {
            rowptr[node] = beg + excl;
            dinv[node] = rsqrtf((float)(v + 1));  // +1 self loop; always > 0
        }
    }
    __syncthreads();
    for (int i = beg + t; i < end; i += 256) {
        int pk = ebuf[i];
        int dloc = pk >> 20;
        int p = beg + atomicAdd(&hoff[dloc], 1);
        esrc[p] = pk & 0xFFFFF;
    }
}

// ================= GEMM1: P1 = (x @ W1) * dinv[row]  [N,128]x[128,64] =================

__global__ __launch_bounds__(256) void k_gemm1(const float* __restrict__ x,
                                               const float* __restrict__ W,
                                               const float* __restrict__ dinv,
                                               float* __restrict__ P, int n) {
    __shared__ float Ws[IN_DIM * HID];  // 32 KB
    const int t = threadIdx.x;
    {
        const float4* W4 = (const float4*)W;
        float4* Ws4 = (float4*)Ws;
#pragma unroll
        for (int i = 0; i < 8; ++i) Ws4[t + 256 * i] = W4[t + 256 * i];
    }
    __syncthreads();

    const int row0 = blockIdx.x * 64;
    const int ty = t >> 4, tx = t & 15;  // 4 rows x 4 cols per thread
    float acc[4][4];
#pragma unroll
    for (int i = 0; i < 4; ++i)
#pragma unroll
        for (int j = 0; j < 4; ++j) acc[i][j] = 0.f;

    const float4* x4 = (const float4*)x;
    int gr[4];
#pragma unroll
    for (int i = 0; i < 4; ++i) {
        int r = row0 + ty * 4 + i;
        gr[i] = r < n ? r : (n - 1);  // clamp for safe load; store is guarded
    }

#pragma unroll 2
    for (int k = 0; k < IN_DIM; k += 4) {
        float aa[4][4];
#pragma unroll
        for (int i = 0; i < 4; ++i) {
            float4 av = x4[(size_t)gr[i] * 32 + (k >> 2)];
            aa[i][0] = av.x; aa[i][1] = av.y; aa[i][2] = av.z; aa[i][3] = av.w;
        }
#pragma unroll
        for (int q = 0; q < 4; ++q) {
            float4 bv = *(const float4*)&Ws[(k + q) * HID + tx * 4];
#pragma unroll
            for (int i = 0; i < 4; ++i) {
                acc[i][0] = fmaf(aa[i][q], bv.x, acc[i][0]);
                acc[i][1] = fmaf(aa[i][q], bv.y, acc[i][1]);
                acc[i][2] = fmaf(aa[i][q], bv.z, acc[i][2]);
                acc[i][3] = fmaf(aa[i][q], bv.w, acc[i][3]);
            }
        }
    }

#pragma unroll
    for (int i = 0; i < 4; ++i) {
        int r = row0 + ty * 4 + i;
        if (r < n) {
            float s = dinv[r];
            float4 o = make_float4(acc[i][0] * s, acc[i][1] * s, acc[i][2] * s, acc[i][3] * s);
            *(float4*)&P[(size_t)r * HID + tx * 4] = o;
        }
    }
}

// ================= GEMM2: P2 = (h @ W2) * dinv[row]  [N,64]x[64,40] =================

__global__ __launch_bounds__(256) void k_gemm2(const float* __restrict__ h,
                                               const float* __restrict__ W,
                                               const float* __restrict__ dinv,
                                               float* __restrict__ P, int n) {
    __shared__ float Ws[HID * 48];  // padded cols, 12 KB
    const int t = threadIdx.x;
#pragma unroll
    for (int i = 0; i < 12; ++i) {
        int idx = t + 256 * i;
        int r = idx / 48, c = idx - r * 48;
        Ws[idx] = (c < ODIM) ? W[r * ODIM + c] : 0.f;
    }
    __syncthreads();

    const int row0 = blockIdx.x * 64;
    const int ty = t >> 4, tx = t & 15;  // 4 rows x 3 cols
    float acc[4][3];
#pragma unroll
    for (int i = 0; i < 4; ++i)
#pragma unroll
        for (int j = 0; j < 3; ++j) acc[i][j] = 0.f;

    const float4* h4 = (const float4*)h;
    int gr[4];
#pragma unroll
    for (int i = 0; i < 4; ++i) {
        int r = row0 + ty * 4 + i;
        gr[i] = r < n ? r : (n - 1);
    }

#pragma unroll 2
    for (int k = 0; k < HID; k += 4) {
        float aa[4][4];
#pragma unroll
        for (int i = 0; i < 4; ++i) {
            float4 av = h4[(size_t)gr[i] * 16 + (k >> 2)];
            aa[i][0] = av.x; aa[i][1] = av.y; aa[i][2] = av.z; aa[i][3] = av.w;
        }
#pragma unroll
        for (int q = 0; q < 4; ++q) {
            const float* wr = &Ws[(k + q) * 48 + tx * 3];
            float b0 = wr[0], b1v = wr[1], b2v = wr[2];
#pragma unroll
            for (int i = 0; i < 4; ++i) {
                acc[i][0] = fmaf(aa[i][q], b0, acc[i][0]);
                acc[i][1] = fmaf(aa[i][q], b1v, acc[i][1]);
                acc[i][2] = fmaf(aa[i][q], b2v, acc[i][2]);
            }
        }
    }

#pragma unroll
    for (int i = 0; i < 4; ++i) {
        int r = row0 + ty * 4 + i;
        if (r < n) {
            float s = dinv[r];
#pragma unroll
            for (int j = 0; j < 3; ++j) {
                int c = tx * 3 + j;
                if (c < ODIM) P[(size_t)r * ODIM + c] = acc[i][j] * s;
            }
        }
    }
}

// ================= fused CSR aggregation + finalize (node-parallel pull) =================
// layer1: one 64-lane wave per node. Lane l = (edge-slot grp = l>>4, float4-chunk q = l&15).
// Each iteration gathers 4 full P-rows (1 KB/wave); unroll 4 -> 16 gathers in flight.
// h[d] = relu(dinv[d] * (sum_{s in N(d)} P[s] + P[d]) + b)

__global__ __launch_bounds__(256) void k_agg1(const int* __restrict__ rowptr,
                                              const int* __restrict__ esrc,
                                              const float4* __restrict__ P4,
                                              const float* __restrict__ dinv,
                                              const float* __restrict__ b,
                                              float4* __restrict__ h4, int n) {
    const int t = threadIdx.x;
    const int lane = t & 63;
    const int node = blockIdx.x * 4 + (t >> 6);
    if (node >= n) return;
    const int grp = lane >> 4, q = lane & 15;  // 16 float4 = 64 feats
    const int beg = rowptr[node], end = rowptr[node + 1];

    float4 acc = make_float4(0.f, 0.f, 0.f, 0.f);
    int j = beg;
#pragma unroll 4
    for (; j + 3 < end; j += 4) {
        int s = esrc[j + grp];
        float4 v = P4[(size_t)s * 16 + q];
        acc.x += v.x; acc.y += v.y; acc.z += v.z; acc.w += v.w;
    }
    if (j + grp < end) {
        int s = esrc[j + grp];
        float4 v = P4[(size_t)s * 16 + q];
        acc.x += v.x; acc.y += v.y; acc.z += v.z; acc.w += v.w;
    }
    // combine the 4 edge-slots: xor 16 then xor 32
    acc.x += __shfl_xor(acc.x, 16); acc.y += __shfl_xor(acc.y, 16);
    acc.z += __shfl_xor(acc.z, 16); acc.w += __shfl_xor(acc.w, 16);
    acc.x += __shfl_xor(acc.x, 32); acc.y += __shfl_xor(acc.y, 32);
    acc.z += __shfl_xor(acc.z, 32); acc.w += __shfl_xor(acc.w, 32);

    if (grp == 0) {  // only the storing group touches self-row/dinv/bias
        float4 self = P4[(size_t)node * 16 + q];
        float di = dinv[node];
        float4 bb = *(const float4*)&b[q * 4];
        float4 r;
        r.x = fmaxf(fmaf(di, acc.x + self.x, bb.x), 0.f);
        r.y = fmaxf(fmaf(di, acc.y + self.y, bb.y), 0.f);
        r.z = fmaxf(fmaf(di, acc.z + self.z, bb.z), 0.f);
        r.w = fmaxf(fmaf(di, acc.w + self.w, bb.w), 0.f);
        h4[(size_t)node * 16 + q] = r;  // lanes 0-15: 256B store
    }
}

// layer2: 40 feats = 10 float4 per row (stride 160B, 16B aligned).
// 6 edge-slots x 10 chunks = 60 active lanes (grp = lane/10, q = lane%10).
// 6-way combine: 3 shuffle steps (+30, +20, +10), result lands on lanes 0..9.

__global__ __launch_bounds__(256) void k_agg2(const int* __restrict__ rowptr,
                                              const int* __restrict__ esrc,
                                              const float4* __restrict__ P4,
                                              const float* __restrict__ dinv,
                                              const float* __restrict__ b,
                                              float4* __restrict__ out4, int n) {
    const int t = threadIdx.x;
    const int lane = t & 63;
    const int node = blockIdx.x * 4 + (t >> 6);
    if (node >= n) return;
    const int grp = lane / 10;          // 0..6 (lanes 60-63: grp 6, inactive)
    const int q = lane - grp * 10;      // 0..9
    const bool act = grp < 6;
    const int beg = rowptr[node], end = rowptr[node + 1];

    float4 acc = make_float4(0.f, 0.f, 0.f, 0.f);
    int j = beg;
#pragma unroll 4
    for (; j + 5 < end; j += 6) {
        if (act) {
            int s = esrc[j + grp];
            float4 v = P4[(size_t)s * 10 + q];
            acc.x += v.x; acc.y += v.y; acc.z += v.z; acc.w += v.w;
        }
    }
    if (act && j + grp < end) {
        int s = esrc[j + grp];
        float4 v = P4[(size_t)s * 10 + q];
        acc.x += v.x; acc.y += v.y; acc.z += v.z; acc.w += v.w;
    }

    // grp0 += grp3, grp1 += grp4, grp2 += grp5   (lanes < 30 read lane+30)
    {
        float tx_ = __shfl(acc.x, lane + 30), ty_ = __shfl(acc.y, lane + 30);
        float tz_ = __shfl(acc.z, lane + 30), tw_ = __shfl(acc.w, lane + 30);
        if (lane < 30) { acc.x += tx_; acc.y += ty_; acc.z += tz_; acc.w += tw_; }
    }
    // grp0 += grp2(+grp5)
    {
        float tx_ = __shfl(acc.x, lane + 20), ty_ = __shfl(acc.y, lane + 20);
        float tz_ = __shfl(acc.z, lane + 20), tw_ = __shfl(acc.w, lane + 20);
        if (lane < 10) { acc.x += tx_; acc.y += ty_; acc.z += tz_; acc.w += tw_; }
    }
    // grp0 += grp1(+grp4)
    {
        float tx_ = __shfl(acc.x, lane + 10), ty_ = __shfl(acc.y, lane + 10);
        float tz_ = __shfl(acc.z, lane + 10), tw_ = __shfl(acc.w, lane + 10);
        if (lane < 10) { acc.x += tx_; acc.y += ty_; acc.z += tz_; acc.w += tw_; }
    }

    if (lane < 10) {  // full sums live here
        float4 self = P4[(size_t)node * 10 + q];
        float di = dinv[node];
        float4 bb = *(const float4*)&b[q * 4];
        float4 r;
        r.x = fmaf(di, acc.x + self.x, bb.x);
        r.y = fmaf(di, acc.y + self.y, bb.y);
        r.z = fmaf(di, acc.z + self.z, bb.z);
        r.w = fmaf(di, acc.w + self.w, bb.w);
        out4[(size_t)node * 10 + q] = r;  // 10 lanes: 160B store
    }
}

// ================= launch =================

extern "C" void kernel_launch(void* const* d_in, const int* in_sizes, int n_in,
                              void* d_out, int out_size, void* d_ws, size_t ws_size,
                              hipStream_t stream) {
    const float* x  = (const float*)d_in[0];
    const int*   ei = (const int*)d_in[1];
    const float* W1 = (const float*)d_in[2];
    const float* b1 = (const float*)d_in[3];
    const float* W2 = (const float*)d_in[4];
    const float* b2 = (const float*)d_in[5];

    const int n = in_sizes[0] / IN_DIM;   // 100000
    const int e = in_sizes[1] / 2;        // 1600000
    const int* src = ei;
    const int* dst = ei + e;
    const int nb = (n + BSZ - 1) >> BSH;  // 782

    auto align = [](size_t b) { return (b + 255) & ~(size_t)255; };
    char* ws = (char*)d_ws;
    size_t o = 0;
    int*   bcnt  = (int*)(ws + o);   o += (size_t)NBMAX * 4;   // bcnt + bcur: one memset
    int*   bcur  = (int*)(ws + o);   o += (size_t)NBMAX * 4;
    o = align(o);
    int*   bbase = (int*)(ws + o);   o += align((size_t)NBMAX * 4);
    float* dinv  = (float*)(ws + o); o += align((size_t)n * 4);
    int*   rowptr= (int*)(ws + o);   o += align((size_t)(n + 1) * 4);
    int*   ebuf  = (int*)(ws + o);   o += align((size_t)e * 4);          // 6.4 MB
    int*   esrc  = (int*)(ws + o);   o += align((size_t)e * 4);          // 6.4 MB
    float* P1    = (float*)(ws + o); o += align((size_t)n * HID * 4);    // 25.6 MB (reused as P2)
    float* h     = (float*)(ws + o); o += align((size_t)n * HID * 4);    // 25.6 MB
    // total ~65 MB

    float* out = (float*)d_out;

    hipMemsetAsync(bcnt, 0, (size_t)2 * NBMAX * 4, stream);  // bcnt + bcur

    // ---- bucketed CSR build (+dinv fused into sort) ----
    k_bcount<<<1024, 256, 0, stream>>>(dst, bcnt, e, nb);
    k_bscan<<<1, 1024, 0, stream>>>(bcnt, bbase, rowptr, n, nb, e);
    k_bscatter<<<1024, 256, 0, stream>>>(src, dst, bbase, bcur, ebuf, e);
    k_bsort<<<nb, 256, 0, stream>>>(ebuf, bbase, esrc, rowptr, dinv, n, nb, e);

    // ---- layer 1 ----
    k_gemm1<<<(n + 63) / 64, 256, 0, stream>>>(x, W1, dinv, P1, n);
    k_agg1<<<(n + 3) / 4, 256, 0, stream>>>(rowptr, esrc, (const float4*)P1, dinv, b1,
                                            (float4*)h, n);

    // ---- layer 2 (P2 reuses P1 buffer) ----
    k_gemm2<<<(n + 63) / 64, 256, 0, stream>>>(h, W2, dinv, P1, n);
    k_agg2<<<(n + 3) / 4, 256, 0, stream>>>(rowptr, esrc, (const float4*)P1, dinv, b2,
                                            (float4*)out, n);
}

// Round 9
// 487.499 us; speedup vs baseline: 3.5431x; 1.4239x over previous
//
#include <hip/hip_runtime.h>

#define IN_DIM 128
#define HID 64
#define ODIM 40
#define BSH 7
#define BSZ 128        // nodes per bucket
#define NBMAX 1024     // max buckets (n <= 131072)
#define NBLK 128       // partition blocks (radix-scatter chunking)

// ================= pass 1: per-(block,bucket) histogram =================
// histM layout: [bucket][blk]  (bucket-major -> flat exclusive scan = final positions)

__global__ __launch_bounds__(256) void k_hist(const int* __restrict__ dst,
                                              int* __restrict__ histM, int e, int nb) {
    __shared__ int hist[NBMAX];
    const int t = threadIdx.x;
    const int blk = blockIdx.x;
    for (int i = t; i < nb; i += 256) hist[i] = 0;
    __syncthreads();
    const int chunk = (e + NBLK - 1) / NBLK;
    const int beg = blk * chunk, end = min(beg + chunk, e);
    for (int i = beg + t; i < end; i += 256)
        atomicAdd(&hist[dst[i] >> BSH], 1);
    __syncthreads();
    for (int i = t; i < nb; i += 256) histM[i * NBLK + blk] = hist[i];
}

// ================= pass 2: exclusive scan of histM (nb*NBLK elems) =================
// offM[b*NBLK+blk] = write base for block blk's edges of bucket b.
// Also emits bbase[b] (bucket starts) and rowptr[n] = e.

__global__ __launch_bounds__(1024) void k_scan2(const int* __restrict__ histM,
                                                int* __restrict__ offM,
                                                int* __restrict__ bbase,
                                                int* __restrict__ rowptr,
                                                int n, int nb, int e) {
    __shared__ int part[1024];
    const int tid = threadIdx.x;
    const int total = nb * NBLK;
    const int per = (total + 1023) / 1024;
    const int base = tid * per;
    const int lim = min(base + per, total);
    int s = 0;
    for (int i = base; i < lim; ++i) s += histM[i];
    part[tid] = s;
    __syncthreads();
    for (int off = 1; off < 1024; off <<= 1) {
        int tv = (tid >= off) ? part[tid - off] : 0;
        __syncthreads();
        part[tid] += tv;
        __syncthreads();
    }
    int run = part[tid] - s;  // exclusive prefix of this thread's range
    for (int i = base; i < lim; ++i) {
        if ((i & (NBLK - 1)) == 0) bbase[i >> 7] = run;  // NBLK==128==2^7
        offM[i] = run;
        run += histM[i];
    }
    if (tid == 0) rowptr[n] = e;
}

// ================= pass 3: scatter via LDS cursors (no global atomics) =================
// packed: src | (local_dst << 20)   (src < 2^20, local_dst < 128)

__global__ __launch_bounds__(256) void k_bscatter2(const int* __restrict__ src,
                                                   const int* __restrict__ dst,
                                                   const int* __restrict__ offM,
                                                   int* __restrict__ ebuf, int e, int nb) {
    __shared__ int lcur[NBMAX];
    const int t = threadIdx.x;
    const int blk = blockIdx.x;
    for (int i = t; i < nb; i += 256) lcur[i] = offM[i * NBLK + blk];
    __syncthreads();
    const int chunk = (e + NBLK - 1) / NBLK;
    const int beg = blk * chunk, end = min(beg + chunk, e);
    for (int i = beg + t; i < end; i += 256) {
        int s = src[i], d = dst[i];
        int b = d >> BSH;
        int p = atomicAdd(&lcur[b], 1);  // LDS atomic: block-local contention only
        ebuf[p] = s | ((d & (BSZ - 1)) << 20);
    }
}

// ================= per-bucket counting sort -> CSR (+rowptr, dinv) =================

__global__ __launch_bounds__(256) void k_bsort(const int* __restrict__ ebuf,
                                               const int* __restrict__ bbase,
                                               int* __restrict__ esrc,
                                               int* __restrict__ rowptr,
                                               float* __restrict__ dinv,
                                               int n, int nb, int e) {
    __shared__ int hist[BSZ];
    __shared__ int sc[BSZ];
    __shared__ int hoff[BSZ];
    const int t = threadIdx.x;
    const int b = blockIdx.x;
    const int node0 = b << BSH;
    if (t < BSZ) hist[t] = 0;
    __syncthreads();
    const int beg = bbase[b];
    const int end = (b + 1 < nb) ? bbase[b + 1] : e;
    for (int i = beg + t; i < end; i += 256)
        atomicAdd(&hist[ebuf[i] >> 20], 1);
    __syncthreads();
    int v = (t < BSZ) ? hist[t] : 0;
    if (t < BSZ) sc[t] = v;
    __syncthreads();
    for (int off = 1; off < BSZ; off <<= 1) {
        int add = (t < BSZ && t >= off) ? sc[t - off] : 0;
        __syncthreads();
        if (t < BSZ) sc[t] += add;
        __syncthreads();
    }
    if (t < BSZ) {
        int excl = sc[t] - v;
        hoff[t] = excl;  // cursor
        int node = node0 + t;
        if (node < n) {
            rowptr[node] = beg + excl;
            dinv[node] = rsqrtf((float)(v + 1));  // +1 self loop; always > 0
        }
    }
    __syncthreads();
    for (int i = beg + t; i < end; i += 256) {
        int pk = ebuf[i];
        int dloc = pk >> 20;
        int p = beg + atomicAdd(&hoff[dloc], 1);
        esrc[p] = pk & 0xFFFFF;
    }
}

// ================= GEMM1: P1 = (x @ W1) * dinv[row]  [N,128]x[128,64] =================

__global__ __launch_bounds__(256) void k_gemm1(const float* __restrict__ x,
                                               const float* __restrict__ W,
                                               const float* __restrict__ dinv,
                                               float* __restrict__ P, int n) {
    __shared__ float Ws[IN_DIM * HID];  // 32 KB
    const int t = threadIdx.x;
    {
        const float4* W4 = (const float4*)W;
        float4* Ws4 = (float4*)Ws;
#pragma unroll
        for (int i = 0; i < 8; ++i) Ws4[t + 256 * i] = W4[t + 256 * i];
    }
    __syncthreads();

    const int row0 = blockIdx.x * 64;
    const int ty = t >> 4, tx = t & 15;  // 4 rows x 4 cols per thread
    float acc[4][4];
#pragma unroll
    for (int i = 0; i < 4; ++i)
#pragma unroll
        for (int j = 0; j < 4; ++j) acc[i][j] = 0.f;

    const float4* x4 = (const float4*)x;
    int gr[4];
#pragma unroll
    for (int i = 0; i < 4; ++i) {
        int r = row0 + ty * 4 + i;
        gr[i] = r < n ? r : (n - 1);  // clamp for safe load; store is guarded
    }

#pragma unroll 2
    for (int k = 0; k < IN_DIM; k += 4) {
        float aa[4][4];
#pragma unroll
        for (int i = 0; i < 4; ++i) {
            float4 av = x4[(size_t)gr[i] * 32 + (k >> 2)];
            aa[i][0] = av.x; aa[i][1] = av.y; aa[i][2] = av.z; aa[i][3] = av.w;
        }
#pragma unroll
        for (int q = 0; q < 4; ++q) {
            float4 bv = *(const float4*)&Ws[(k + q) * HID + tx * 4];
#pragma unroll
            for (int i = 0; i < 4; ++i) {
                acc[i][0] = fmaf(aa[i][q], bv.x, acc[i][0]);
                acc[i][1] = fmaf(aa[i][q], bv.y, acc[i][1]);
                acc[i][2] = fmaf(aa[i][q], bv.z, acc[i][2]);
                acc[i][3] = fmaf(aa[i][q], bv.w, acc[i][3]);
            }
        }
    }

#pragma unroll
    for (int i = 0; i < 4; ++i) {
        int r = row0 + ty * 4 + i;
        if (r < n) {
            float s = dinv[r];
            float4 o = make_float4(acc[i][0] * s, acc[i][1] * s, acc[i][2] * s, acc[i][3] * s);
            *(float4*)&P[(size_t)r * HID + tx * 4] = o;
        }
    }
}

// ================= GEMM2: P2 = (h @ W2) * dinv[row]  [N,64]x[64,40] =================

__global__ __launch_bounds__(256) void k_gemm2(const float* __restrict__ h,
                                               const float* __restrict__ W,
                                               const float* __restrict__ dinv,
                                               float* __restrict__ P, int n) {
    __shared__ float Ws[HID * 48];  // padded cols, 12 KB
    const int t = threadIdx.x;
#pragma unroll
    for (int i = 0; i < 12; ++i) {
        int idx = t + 256 * i;
        int r = idx / 48, c = idx - r * 48;
        Ws[idx] = (c < ODIM) ? W[r * ODIM + c] : 0.f;
    }
    __syncthreads();

    const int row0 = blockIdx.x * 64;
    const int ty = t >> 4, tx = t & 15;  // 4 rows x 3 cols
    float acc[4][3];
#pragma unroll
    for (int i = 0; i < 4; ++i)
#pragma unroll
        for (int j = 0; j < 3; ++j) acc[i][j] = 0.f;

    const float4* h4 = (const float4*)h;
    int gr[4];
#pragma unroll
    for (int i = 0; i < 4; ++i) {
        int r = row0 + ty * 4 + i;
        gr[i] = r < n ? r : (n - 1);
    }

#pragma unroll 2
    for (int k = 0; k < HID; k += 4) {
        float aa[4][4];
#pragma unroll
        for (int i = 0; i < 4; ++i) {
            float4 av = h4[(size_t)gr[i] * 16 + (k >> 2)];
            aa[i][0] = av.x; aa[i][1] = av.y; aa[i][2] = av.z; aa[i][3] = av.w;
        }
#pragma unroll
        for (int q = 0; q < 4; ++q) {
            const float* wr = &Ws[(k + q) * 48 + tx * 3];
            float b0 = wr[0], b1v = wr[1], b2v = wr[2];
#pragma unroll
            for (int i = 0; i < 4; ++i) {
                acc[i][0] = fmaf(aa[i][q], b0, acc[i][0]);
                acc[i][1] = fmaf(aa[i][q], b1v, acc[i][1]);
                acc[i][2] = fmaf(aa[i][q], b2v, acc[i][2]);
            }
        }
    }

#pragma unroll
    for (int i = 0; i < 4; ++i) {
        int r = row0 + ty * 4 + i;
        if (r < n) {
            float s = dinv[r];
#pragma unroll
            for (int j = 0; j < 3; ++j) {
                int c = tx * 3 + j;
                if (c < ODIM) P[(size_t)r * ODIM + c] = acc[i][j] * s;
            }
        }
    }
}

// ================= fused CSR aggregation + finalize (node-parallel pull) =================
// layer1: one 64-lane wave per node. Lane l = (edge-slot grp = l>>4, float4-chunk q = l&15).
// h[d] = relu(dinv[d] * (sum_{s in N(d)} P[s] + P[d]) + b)

__global__ __launch_bounds__(256) void k_agg1(const int* __restrict__ rowptr,
                                              const int* __restrict__ esrc,
                                              const float4* __restrict__ P4,
                                              const float* __restrict__ dinv,
                                              const float* __restrict__ b,
                                              float4* __restrict__ h4, int n) {
    const int t = threadIdx.x;
    const int lane = t & 63;
    const int node = blockIdx.x * 4 + (t >> 6);
    if (node >= n) return;
    const int grp = lane >> 4, q = lane & 15;  // 16 float4 = 64 feats
    const int beg = rowptr[node], end = rowptr[node + 1];

    float4 acc = make_float4(0.f, 0.f, 0.f, 0.f);
    int j = beg;
#pragma unroll 4
    for (; j + 3 < end; j += 4) {
        int s = esrc[j + grp];
        float4 v = P4[(size_t)s * 16 + q];
        acc.x += v.x; acc.y += v.y; acc.z += v.z; acc.w += v.w;
    }
    if (j + grp < end) {
        int s = esrc[j + grp];
        float4 v = P4[(size_t)s * 16 + q];
        acc.x += v.x; acc.y += v.y; acc.z += v.z; acc.w += v.w;
    }
    // combine the 4 edge-slots: xor 16 then xor 32
    acc.x += __shfl_xor(acc.x, 16); acc.y += __shfl_xor(acc.y, 16);
    acc.z += __shfl_xor(acc.z, 16); acc.w += __shfl_xor(acc.w, 16);
    acc.x += __shfl_xor(acc.x, 32); acc.y += __shfl_xor(acc.y, 32);
    acc.z += __shfl_xor(acc.z, 32); acc.w += __shfl_xor(acc.w, 32);

    if (grp == 0) {  // only the storing group touches self-row/dinv/bias
        float4 self = P4[(size_t)node * 16 + q];
        float di = dinv[node];
        float4 bb = *(const float4*)&b[q * 4];
        float4 r;
        r.x = fmaxf(fmaf(di, acc.x + self.x, bb.x), 0.f);
        r.y = fmaxf(fmaf(di, acc.y + self.y, bb.y), 0.f);
        r.z = fmaxf(fmaf(di, acc.z + self.z, bb.z), 0.f);
        r.w = fmaxf(fmaf(di, acc.w + self.w, bb.w), 0.f);
        h4[(size_t)node * 16 + q] = r;  // lanes 0-15: 256B store
    }
}

// layer2: 40 feats = 10 float4 per row (stride 160B, 16B aligned).
// 6 edge-slots x 10 chunks = 60 active lanes; 3-step combine lands on lanes 0..9.

__global__ __launch_bounds__(256) void k_agg2(const int* __restrict__ rowptr,
                                              const int* __restrict__ esrc,
                                              const float4* __restrict__ P4,
                                              const float* __restrict__ dinv,
                                              const float* __restrict__ b,
                                              float4* __restrict__ out4, int n) {
    const int t = threadIdx.x;
    const int lane = t & 63;
    const int node = blockIdx.x * 4 + (t >> 6);
    if (node >= n) return;
    const int grp = lane / 10;          // 0..6 (lanes 60-63: grp 6, inactive)
    const int q = lane - grp * 10;      // 0..9
    const bool act = grp < 6;
    const int beg = rowptr[node], end = rowptr[node + 1];

    float4 acc = make_float4(0.f, 0.f, 0.f, 0.f);
    int j = beg;
#pragma unroll 4
    for (; j + 5 < end; j += 6) {
        if (act) {
            int s = esrc[j + grp];
            float4 v = P4[(size_t)s * 10 + q];
            acc.x += v.x; acc.y += v.y; acc.z += v.z; acc.w += v.w;
        }
    }
    if (act && j + grp < end) {
        int s = esrc[j + grp];
        float4 v = P4[(size_t)s * 10 + q];
        acc.x += v.x; acc.y += v.y; acc.z += v.z; acc.w += v.w;
    }

    {
        float tx_ = __shfl(acc.x, lane + 30), ty_ = __shfl(acc.y, lane + 30);
        float tz_ = __shfl(acc.z, lane + 30), tw_ = __shfl(acc.w, lane + 30);
        if (lane < 30) { acc.x += tx_; acc.y += ty_; acc.z += tz_; acc.w += tw_; }
    }
    {
        float tx_ = __shfl(acc.x, lane + 20), ty_ = __shfl(acc.y, lane + 20);
        float tz_ = __shfl(acc.z, lane + 20), tw_ = __shfl(acc.w, lane + 20);
        if (lane < 10) { acc.x += tx_; acc.y += ty_; acc.z += tz_; acc.w += tw_; }
    }
    {
        float tx_ = __shfl(acc.x, lane + 10), ty_ = __shfl(acc.y, lane + 10);
        float tz_ = __shfl(acc.z, lane + 10), tw_ = __shfl(acc.w, lane + 10);
        if (lane < 10) { acc.x += tx_; acc.y += ty_; acc.z += tz_; acc.w += tw_; }
    }

    if (lane < 10) {  // full sums live here
        float4 self = P4[(size_t)node * 10 + q];
        float di = dinv[node];
        float4 bb = *(const float4*)&b[q * 4];
        float4 r;
        r.x = fmaf(di, acc.x + self.x, bb.x);
        r.y = fmaf(di, acc.y + self.y, bb.y);
        r.z = fmaf(di, acc.z + self.z, bb.z);
        r.w = fmaf(di, acc.w + self.w, bb.w);
        out4[(size_t)node * 10 + q] = r;  // 10 lanes: 160B store
    }
}

// ================= launch =================

extern "C" void kernel_launch(void* const* d_in, const int* in_sizes, int n_in,
                              void* d_out, int out_size, void* d_ws, size_t ws_size,
                              hipStream_t stream) {
    const float* x  = (const float*)d_in[0];
    const int*   ei = (const int*)d_in[1];
    const float* W1 = (const float*)d_in[2];
    const float* b1 = (const float*)d_in[3];
    const float* W2 = (const float*)d_in[4];
    const float* b2 = (const float*)d_in[5];

    const int n = in_sizes[0] / IN_DIM;   // 100000
    const int e = in_sizes[1] / 2;        // 1600000
    const int* src = ei;
    const int* dst = ei + e;
    const int nb = (n + BSZ - 1) >> BSH;  // 782

    auto align = [](size_t b) { return (b + 255) & ~(size_t)255; };
    char* ws = (char*)d_ws;
    size_t o = 0;
    int*   histM = (int*)(ws + o);   o += align((size_t)NBMAX * NBLK * 4);  // 512 KB
    int*   offM  = (int*)(ws + o);   o += align((size_t)NBMAX * NBLK * 4);  // 512 KB
    int*   bbase = (int*)(ws + o);   o += align((size_t)NBMAX * 4);
    float* dinv  = (float*)(ws + o); o += align((size_t)n * 4);
    int*   rowptr= (int*)(ws + o);   o += align((size_t)(n + 1) * 4);
    int*   ebuf  = (int*)(ws + o);   o += align((size_t)e * 4);             // 6.4 MB
    int*   esrc  = (int*)(ws + o);   o += align((size_t)e * 4);             // 6.4 MB
    float* P1    = (float*)(ws + o); o += align((size_t)n * HID * 4);       // 25.6 MB (reused as P2)
    float* h     = (float*)(ws + o); o += align((size_t)n * HID * 4);       // 25.6 MB
    // total ~66 MB; no memset needed (all build buffers fully written each call)

    float* out = (float*)d_out;

    // ---- radix-partition CSR build (no global atomics) ----
    k_hist<<<NBLK, 256, 0, stream>>>(dst, histM, e, nb);
    k_scan2<<<1, 1024, 0, stream>>>(histM, offM, bbase, rowptr, n, nb, e);
    k_bscatter2<<<NBLK, 256, 0, stream>>>(src, dst, offM, ebuf, e, nb);
    k_bsort<<<nb, 256, 0, stream>>>(ebuf, bbase, esrc, rowptr, dinv, n, nb, e);

    // ---- layer 1 ----
    k_gemm1<<<(n + 63) / 64, 256, 0, stream>>>(x, W1, dinv, P1, n);
    k_agg1<<<(n + 3) / 4, 256, 0, stream>>>(rowptr, esrc, (const float4*)P1, dinv, b1,
                                            (float4*)h, n);

    // ---- layer 2 (P2 reuses P1 buffer) ----
    k_gemm2<<<(n + 63) / 64, 256, 0, stream>>>(h, W2, dinv, P1, n);
    k_agg2<<<(n + 3) / 4, 256, 0, stream>>>(rowptr, esrc, (const float4*)P1, dinv, b2,
                                            (float4*)out, n);
}

// Round 10
// 337.428 us; speedup vs baseline: 5.1188x; 1.4448x over previous
//
#include <hip/hip_runtime.h>

#define IN_DIM 128
#define HID 64
#define ODIM 40
#define BSH 7
#define BSZ 128        // nodes per bucket
#define NBMAX 1024     // max buckets (n <= 131072)
#define NBLK 128       // partition blocks (radix-scatter chunking)
#define SCH 2048       // scan chunk: 256 thr x 8 elems

// ================= pass 1: per-(block,bucket) histogram =================
// histM layout: [bucket][blk]  (bucket-major -> flat exclusive scan = final positions)

__global__ __launch_bounds__(256) void k_hist(const int* __restrict__ dst,
                                              int* __restrict__ histM, int e, int nb) {
    __shared__ int hist[NBMAX];
    const int t = threadIdx.x;
    const int blk = blockIdx.x;
    for (int i = t; i < nb; i += 256) hist[i] = 0;
    __syncthreads();
    const int chunk = (e + NBLK - 1) / NBLK;
    const int beg = blk * chunk, end = min(beg + chunk, e);
    for (int i = beg + t; i < end; i += 256)
        atomicAdd(&hist[dst[i] >> BSH], 1);
    __syncthreads();
    for (int i = t; i < nb; i += 256) histM[i * NBLK + blk] = hist[i];
}

// ================= pass 2: hierarchical exclusive scan of histM =================
// total = nb*NBLK (~100K). offM[b*NBLK+blk] = write base for (bucket b, block blk).
// Emits bbase[b] at each 128-aligned index; rowptr[n] = e.

__global__ __launch_bounds__(256) void k_s1(const int* __restrict__ histM,
                                            int* __restrict__ csum, int total) {
    __shared__ int red[256];
    const int t = threadIdx.x;
    const int base = blockIdx.x * SCH + t * 8;
    int s = 0;
#pragma unroll
    for (int j = 0; j < 8; ++j) {
        int idx = base + j;
        if (idx < total) s += histM[idx];
    }
    red[t] = s;
    __syncthreads();
    for (int off = 128; off > 0; off >>= 1) {
        if (t < off) red[t] += red[t + off];
        __syncthreads();
    }
    if (t == 0) csum[blockIdx.x] = red[0];
}

__global__ __launch_bounds__(256) void k_s2(int* __restrict__ csum, int nchunks,
                                            int* __restrict__ rowptr, int n, int e) {
    __shared__ int tmp[256];
    const int tid = threadIdx.x;
    int v = (tid < nchunks) ? csum[tid] : 0;
    tmp[tid] = v;
    __syncthreads();
    for (int off = 1; off < 256; off <<= 1) {
        int t_ = (tid >= off) ? tmp[tid - off] : 0;
        __syncthreads();
        tmp[tid] += t_;
        __syncthreads();
    }
    if (tid < nchunks) csum[tid] = tmp[tid] - v;  // exclusive
    if (tid == 0) rowptr[n] = e;
}

__global__ __launch_bounds__(256) void k_s3(const int* __restrict__ histM,
                                            const int* __restrict__ csum,
                                            int* __restrict__ offM,
                                            int* __restrict__ bbase, int total) {
    __shared__ int tsum[256];
    const int t = threadIdx.x;
    const int base = blockIdx.x * SCH + t * 8;
    int v[8];
#pragma unroll
    for (int j = 0; j < 8; ++j) {
        int idx = base + j;
        v[j] = (idx < total) ? histM[idx] : 0;
    }
    int pre[9];
    pre[0] = 0;
#pragma unroll
    for (int j = 0; j < 8; ++j) pre[j + 1] = pre[j] + v[j];
    tsum[t] = pre[8];
    __syncthreads();
    for (int off = 1; off < 256; off <<= 1) {
        int tv = (t >= off) ? tsum[t - off] : 0;
        __syncthreads();
        tsum[t] += tv;
        __syncthreads();
    }
    const int b0 = csum[blockIdx.x] + (tsum[t] - pre[8]);
#pragma unroll
    for (int j = 0; j < 8; ++j) {
        int idx = base + j;
        if (idx < total) {
            int val = b0 + pre[j];
            offM[idx] = val;
            if ((idx & (NBLK - 1)) == 0) bbase[idx >> 7] = val;  // NBLK==128==2^7
        }
    }
}

// ================= pass 3: scatter via LDS cursors (no global atomics) =================
// packed: src | (local_dst << 20)   (src < 2^20, local_dst < 128)

__global__ __launch_bounds__(256) void k_bscatter2(const int* __restrict__ src,
                                                   const int* __restrict__ dst,
                                                   const int* __restrict__ offM,
                                                   int* __restrict__ ebuf, int e, int nb) {
    __shared__ int lcur[NBMAX];
    const int t = threadIdx.x;
    const int blk = blockIdx.x;
    for (int i = t; i < nb; i += 256) lcur[i] = offM[i * NBLK + blk];
    __syncthreads();
    const int chunk = (e + NBLK - 1) / NBLK;
    const int beg = blk * chunk, end = min(beg + chunk, e);
    for (int i = beg + t; i < end; i += 256) {
        int s = src[i], d = dst[i];
        int b = d >> BSH;
        int p = atomicAdd(&lcur[b], 1);  // LDS atomic: block-local contention only
        ebuf[p] = s | ((d & (BSZ - 1)) << 20);
    }
}

// ================= per-bucket counting sort -> CSR (+rowptr, dinv) =================

__global__ __launch_bounds__(256) void k_bsort(const int* __restrict__ ebuf,
                                               const int* __restrict__ bbase,
                                               int* __restrict__ esrc,
                                               int* __restrict__ rowptr,
                                               float* __restrict__ dinv,
                                               int n, int nb, int e) {
    __shared__ int hist[BSZ];
    __shared__ int sc[BSZ];
    __shared__ int hoff[BSZ];
    const int t = threadIdx.x;
    const int b = blockIdx.x;
    const int node0 = b << BSH;
    if (t < BSZ) hist[t] = 0;
    __syncthreads();
    const int beg = bbase[b];
    const int end = (b + 1 < nb) ? bbase[b + 1] : e;
    for (int i = beg + t; i < end; i += 256)
        atomicAdd(&hist[ebuf[i] >> 20], 1);
    __syncthreads();
    int v = (t < BSZ) ? hist[t] : 0;
    if (t < BSZ) sc[t] = v;
    __syncthreads();
    for (int off = 1; off < BSZ; off <<= 1) {
        int add = (t < BSZ && t >= off) ? sc[t - off] : 0;
        __syncthreads();
        if (t < BSZ) sc[t] += add;
        __syncthreads();
    }
    if (t < BSZ) {
        int excl = sc[t] - v;
        hoff[t] = excl;  // cursor
        int node = node0 + t;
        if (node < n) {
            rowptr[node] = beg + excl;
            dinv[node] = rsqrtf((float)(v + 1));  // +1 self loop; always > 0
        }
    }
    __syncthreads();
    for (int i = beg + t; i < end; i += 256) {
        int pk = ebuf[i];
        int dloc = pk >> 20;
        int p = beg + atomicAdd(&hoff[dloc], 1);
        esrc[p] = pk & 0xFFFFF;
    }
}

// ================= GEMM1: P1 = (x @ W1) * dinv[row]  [N,128]x[128,64] =================

__global__ __launch_bounds__(256) void k_gemm1(const float* __restrict__ x,
                                               const float* __restrict__ W,
                                               const float* __restrict__ dinv,
                                               float* __restrict__ P, int n) {
    __shared__ float Ws[IN_DIM * HID];  // 32 KB
    const int t = threadIdx.x;
    {
        const float4* W4 = (const float4*)W;
        float4* Ws4 = (float4*)Ws;
#pragma unroll
        for (int i = 0; i < 8; ++i) Ws4[t + 256 * i] = W4[t + 256 * i];
    }
    __syncthreads();

    const int row0 = blockIdx.x * 64;
    const int ty = t >> 4, tx = t & 15;  // 4 rows x 4 cols per thread
    float acc[4][4];
#pragma unroll
    for (int i = 0; i < 4; ++i)
#pragma unroll
        for (int j = 0; j < 4; ++j) acc[i][j] = 0.f;

    const float4* x4 = (const float4*)x;
    int gr[4];
#pragma unroll
    for (int i = 0; i < 4; ++i) {
        int r = row0 + ty * 4 + i;
        gr[i] = r < n ? r : (n - 1);  // clamp for safe load; store is guarded
    }

#pragma unroll 2
    for (int k = 0; k < IN_DIM; k += 4) {
        float aa[4][4];
#pragma unroll
        for (int i = 0; i < 4; ++i) {
            float4 av = x4[(size_t)gr[i] * 32 + (k >> 2)];
            aa[i][0] = av.x; aa[i][1] = av.y; aa[i][2] = av.z; aa[i][3] = av.w;
        }
#pragma unroll
        for (int q = 0; q < 4; ++q) {
            float4 bv = *(const float4*)&Ws[(k + q) * HID + tx * 4];
#pragma unroll
            for (int i = 0; i < 4; ++i) {
                acc[i][0] = fmaf(aa[i][q], bv.x, acc[i][0]);
                acc[i][1] = fmaf(aa[i][q], bv.y, acc[i][1]);
                acc[i][2] = fmaf(aa[i][q], bv.z, acc[i][2]);
                acc[i][3] = fmaf(aa[i][q], bv.w, acc[i][3]);
            }
        }
    }

#pragma unroll
    for (int i = 0; i < 4; ++i) {
        int r = row0 + ty * 4 + i;
        if (r < n) {
            float s = dinv[r];
            float4 o = make_float4(acc[i][0] * s, acc[i][1] * s, acc[i][2] * s, acc[i][3] * s);
            *(float4*)&P[(size_t)r * HID + tx * 4] = o;
        }
    }
}

// ================= GEMM2: P2 = (h @ W2) * dinv[row]  [N,64]x[64,40] =================

__global__ __launch_bounds__(256) void k_gemm2(const float* __restrict__ h,
                                               const float* __restrict__ W,
                                               const float* __restrict__ dinv,
                                               float* __restrict__ P, int n) {
    __shared__ float Ws[HID * 48];  // padded cols, 12 KB
    const int t = threadIdx.x;
#pragma unroll
    for (int i = 0; i < 12; ++i) {
        int idx = t + 256 * i;
        int r = idx / 48, c = idx - r * 48;
        Ws[idx] = (c < ODIM) ? W[r * ODIM + c] : 0.f;
    }
    __syncthreads();

    const int row0 = blockIdx.x * 64;
    const int ty = t >> 4, tx = t & 15;  // 4 rows x 3 cols
    float acc[4][3];
#pragma unroll
    for (int i = 0; i < 4; ++i)
#pragma unroll
        for (int j = 0; j < 3; ++j) acc[i][j] = 0.f;

    const float4* h4 = (const float4*)h;
    int gr[4];
#pragma unroll
    for (int i = 0; i < 4; ++i) {
        int r = row0 + ty * 4 + i;
        gr[i] = r < n ? r : (n - 1);
    }

#pragma unroll 2
    for (int k = 0; k < HID; k += 4) {
        float aa[4][4];
#pragma unroll
        for (int i = 0; i < 4; ++i) {
            float4 av = h4[(size_t)gr[i] * 16 + (k >> 2)];
            aa[i][0] = av.x; aa[i][1] = av.y; aa[i][2] = av.z; aa[i][3] = av.w;
        }
#pragma unroll
        for (int q = 0; q < 4; ++q) {
            const float* wr = &Ws[(k + q) * 48 + tx * 3];
            float b0 = wr[0], b1v = wr[1], b2v = wr[2];
#pragma unroll
            for (int i = 0; i < 4; ++i) {
                acc[i][0] = fmaf(aa[i][q], b0, acc[i][0]);
                acc[i][1] = fmaf(aa[i][q], b1v, acc[i][1]);
                acc[i][2] = fmaf(aa[i][q], b2v, acc[i][2]);
            }
        }
    }

#pragma unroll
    for (int i = 0; i < 4; ++i) {
        int r = row0 + ty * 4 + i;
        if (r < n) {
            float s = dinv[r];
#pragma unroll
            for (int j = 0; j < 3; ++j) {
                int c = tx * 3 + j;
                if (c < ODIM) P[(size_t)r * ODIM + c] = acc[i][j] * s;
            }
        }
    }
}

// ================= fused CSR aggregation + finalize (node-parallel pull) =================
// layer1: one 64-lane wave per node. Lane l = (edge-slot grp = l>>4, float4-chunk q = l&15).
// h[d] = relu(dinv[d] * (sum_{s in N(d)} P[s] + P[d]) + b)

__global__ __launch_bounds__(256) void k_agg1(const int* __restrict__ rowptr,
                                              const int* __restrict__ esrc,
                                              const float4* __restrict__ P4,
                                              const float* __restrict__ dinv,
                                              const float* __restrict__ b,
                                              float4* __restrict__ h4, int n) {
    const int t = threadIdx.x;
    const int lane = t & 63;
    const int node = blockIdx.x * 4 + (t >> 6);
    if (node >= n) return;
    const int grp = lane >> 4, q = lane & 15;  // 16 float4 = 64 feats
    const int beg = rowptr[node], end = rowptr[node + 1];

    float4 acc = make_float4(0.f, 0.f, 0.f, 0.f);
    int j = beg;
#pragma unroll 4
    for (; j + 3 < end; j += 4) {
        int s = esrc[j + grp];
        float4 v = P4[(size_t)s * 16 + q];
        acc.x += v.x; acc.y += v.y; acc.z += v.z; acc.w += v.w;
    }
    if (j + grp < end) {
        int s = esrc[j + grp];
        float4 v = P4[(size_t)s * 16 + q];
        acc.x += v.x; acc.y += v.y; acc.z += v.z; acc.w += v.w;
    }
    // combine the 4 edge-slots: xor 16 then xor 32
    acc.x += __shfl_xor(acc.x, 16); acc.y += __shfl_xor(acc.y, 16);
    acc.z += __shfl_xor(acc.z, 16); acc.w += __shfl_xor(acc.w, 16);
    acc.x += __shfl_xor(acc.x, 32); acc.y += __shfl_xor(acc.y, 32);
    acc.z += __shfl_xor(acc.z, 32); acc.w += __shfl_xor(acc.w, 32);

    if (grp == 0) {  // only the storing group touches self-row/dinv/bias
        float4 self = P4[(size_t)node * 16 + q];
        float di = dinv[node];
        float4 bb = *(const float4*)&b[q * 4];
        float4 r;
        r.x = fmaxf(fmaf(di, acc.x + self.x, bb.x), 0.f);
        r.y = fmaxf(fmaf(di, acc.y + self.y, bb.y), 0.f);
        r.z = fmaxf(fmaf(di, acc.z + self.z, bb.z), 0.f);
        r.w = fmaxf(fmaf(di, acc.w + self.w, bb.w), 0.f);
        h4[(size_t)node * 16 + q] = r;  // lanes 0-15: 256B store
    }
}

// layer2: 40 feats = 10 float4 per row (stride 160B, 16B aligned).
// 6 edge-slots x 10 chunks = 60 active lanes; 3-step combine lands on lanes 0..9.

__global__ __launch_bounds__(256) void k_agg2(const int* __restrict__ rowptr,
                                              const int* __restrict__ esrc,
                                              const float4* __restrict__ P4,
                                              const float* __restrict__ dinv,
                                              const float* __restrict__ b,
                                              float4* __restrict__ out4, int n) {
    const int t = threadIdx.x;
    const int lane = t & 63;
    const int node = blockIdx.x * 4 + (t >> 6);
    if (node >= n) return;
    const int grp = lane / 10;          // 0..6 (lanes 60-63: grp 6, inactive)
    const int q = lane - grp * 10;      // 0..9
    const bool act = grp < 6;
    const int beg = rowptr[node], end = rowptr[node + 1];

    float4 acc = make_float4(0.f, 0.f, 0.f, 0.f);
    int j = beg;
#pragma unroll 4
    for (; j + 5 < end; j += 6) {
        if (act) {
            int s = esrc[j + grp];
            float4 v = P4[(size_t)s * 10 + q];
            acc.x += v.x; acc.y += v.y; acc.z += v.z; acc.w += v.w;
        }
    }
    if (act && j + grp < end) {
        int s = esrc[j + grp];
        float4 v = P4[(size_t)s * 10 + q];
        acc.x += v.x; acc.y += v.y; acc.z += v.z; acc.w += v.w;
    }

    {
        float tx_ = __shfl(acc.x, lane + 30), ty_ = __shfl(acc.y, lane + 30);
        float tz_ = __shfl(acc.z, lane + 30), tw_ = __shfl(acc.w, lane + 30);
        if (lane < 30) { acc.x += tx_; acc.y += ty_; acc.z += tz_; acc.w += tw_; }
    }
    {
        float tx_ = __shfl(acc.x, lane + 20), ty_ = __shfl(acc.y, lane + 20);
        float tz_ = __shfl(acc.z, lane + 20), tw_ = __shfl(acc.w, lane + 20);
        if (lane < 10) { acc.x += tx_; acc.y += ty_; acc.z += tz_; acc.w += tw_; }
    }
    {
        float tx_ = __shfl(acc.x, lane + 10), ty_ = __shfl(acc.y, lane + 10);
        float tz_ = __shfl(acc.z, lane + 10), tw_ = __shfl(acc.w, lane + 10);
        if (lane < 10) { acc.x += tx_; acc.y += ty_; acc.z += tz_; acc.w += tw_; }
    }

    if (lane < 10) {  // full sums live here
        float4 self = P4[(size_t)node * 10 + q];
        float di = dinv[node];
        float4 bb = *(const float4*)&b[q * 4];
        float4 r;
        r.x = fmaf(di, acc.x + self.x, bb.x);
        r.y = fmaf(di, acc.y + self.y, bb.y);
        r.z = fmaf(di, acc.z + self.z, bb.z);
        r.w = fmaf(di, acc.w + self.w, bb.w);
        out4[(size_t)node * 10 + q] = r;  // 10 lanes: 160B store
    }
}

// ================= launch =================

extern "C" void kernel_launch(void* const* d_in, const int* in_sizes, int n_in,
                              void* d_out, int out_size, void* d_ws, size_t ws_size,
                              hipStream_t stream) {
    const float* x  = (const float*)d_in[0];
    const int*   ei = (const int*)d_in[1];
    const float* W1 = (const float*)d_in[2];
    const float* b1 = (const float*)d_in[3];
    const float* W2 = (const float*)d_in[4];
    const float* b2 = (const float*)d_in[5];

    const int n = in_sizes[0] / IN_DIM;   // 100000
    const int e = in_sizes[1] / 2;        // 1600000
    const int* src = ei;
    const int* dst = ei + e;
    const int nb = (n + BSZ - 1) >> BSH;  // 782
    const int total = nb * NBLK;          // ~100K
    const int nchunks = (total + SCH - 1) / SCH;  // 49

    auto align = [](size_t b) { return (b + 255) & ~(size_t)255; };
    char* ws = (char*)d_ws;
    size_t o = 0;
    int*   histM = (int*)(ws + o);   o += align((size_t)NBMAX * NBLK * 4);  // 512 KB
    int*   offM  = (int*)(ws + o);   o += align((size_t)NBMAX * NBLK * 4);  // 512 KB
    int*   csum  = (int*)(ws + o);   o += align((size_t)256 * 4);
    int*   bbase = (int*)(ws + o);   o += align((size_t)NBMAX * 4);
    float* dinv  = (float*)(ws + o); o += align((size_t)n * 4);
    int*   rowptr= (int*)(ws + o);   o += align((size_t)(n + 1) * 4);
    int*   ebuf  = (int*)(ws + o);   o += align((size_t)e * 4);             // 6.4 MB
    int*   esrc  = (int*)(ws + o);   o += align((size_t)e * 4);             // 6.4 MB
    float* P1    = (float*)(ws + o); o += align((size_t)n * HID * 4);       // 25.6 MB (reused as P2)
    float* h     = (float*)(ws + o); o += align((size_t)n * HID * 4);       // 25.6 MB
    // total ~66 MB; no memset needed (all build buffers fully written each call)

    float* out = (float*)d_out;

    // ---- radix-partition CSR build (no global atomics, hierarchical scan) ----
    k_hist<<<NBLK, 256, 0, stream>>>(dst, histM, e, nb);
    k_s1<<<nchunks, 256, 0, stream>>>(histM, csum, total);
    k_s2<<<1, 256, 0, stream>>>(csum, nchunks, rowptr, n, e);
    k_s3<<<nchunks, 256, 0, stream>>>(histM, csum, offM, bbase, total);
    k_bscatter2<<<NBLK, 256, 0, stream>>>(src, dst, offM, ebuf, e, nb);
    k_bsort<<<nb, 256, 0, stream>>>(ebuf, bbase, esrc, rowptr, dinv, n, nb, e);

    // ---- layer 1 ----
    k_gemm1<<<(n + 63) / 64, 256, 0, stream>>>(x, W1, dinv, P1, n);
    k_agg1<<<(n + 3) / 4, 256, 0, stream>>>(rowptr, esrc, (const float4*)P1, dinv, b1,
                                            (float4*)h, n);

    // ---- layer 2 (P2 reuses P1 buffer) ----
    k_gemm2<<<(n + 63) / 64, 256, 0, stream>>>(h, W2, dinv, P1, n);
    k_agg2<<<(n + 3) / 4, 256, 0, stream>>>(rowptr, esrc, (const float4*)P1, dinv, b2,
                                            (float4*)out, n);
}

// Round 11
// 330.265 us; speedup vs baseline: 5.2299x; 1.0217x over previous
//
#include <hip/hip_runtime.h>

#define IN_DIM 128
#define HID 64
#define ODIM 40
#define BSH 7
#define BSZ 128        // nodes per bucket
#define NBMAX 1024     // max buckets (n <= 131072)
#define NBLK 256       // partition blocks (1 per CU)
#define NBLKSH 8       // log2(NBLK)
#define SCH 2048       // scan chunk: 256 thr x 8 elems

// ================= pass 1: per-(block,bucket) histogram =================
// histM layout: [bucket][blk]  (bucket-major -> flat exclusive scan = final positions)

__global__ __launch_bounds__(256) void k_hist(const int* __restrict__ dst,
                                              int* __restrict__ histM, int e, int nb) {
    __shared__ int hist[NBMAX];
    const int t = threadIdx.x;
    const int blk = blockIdx.x;
    for (int i = t; i < nb; i += 256) hist[i] = 0;
    __syncthreads();
    const int chunk = (e + NBLK - 1) / NBLK;
    const int beg = blk * chunk, end = min(beg + chunk, e);
    for (int i = beg + t; i < end; i += 256)
        atomicAdd(&hist[dst[i] >> BSH], 1);
    __syncthreads();
    for (int i = t; i < nb; i += 256) histM[i * NBLK + blk] = hist[i];
}

// ================= pass 2: hierarchical exclusive scan of histM =================
// total = nb*NBLK (~200K). offM[b*NBLK+blk] = write base for (bucket b, block blk).
// Emits bbase[b] at each NBLK-aligned index; rowptr[n] = e.

__global__ __launch_bounds__(256) void k_s1(const int* __restrict__ histM,
                                            int* __restrict__ csum, int total) {
    __shared__ int red[256];
    const int t = threadIdx.x;
    const int base = blockIdx.x * SCH + t * 8;
    int s = 0;
#pragma unroll
    for (int j = 0; j < 8; ++j) {
        int idx = base + j;
        if (idx < total) s += histM[idx];
    }
    red[t] = s;
    __syncthreads();
    for (int off = 128; off > 0; off >>= 1) {
        if (t < off) red[t] += red[t + off];
        __syncthreads();
    }
    if (t == 0) csum[blockIdx.x] = red[0];
}

__global__ __launch_bounds__(256) void k_s2(int* __restrict__ csum, int nchunks,
                                            int* __restrict__ rowptr, int n, int e) {
    __shared__ int tmp[256];
    const int tid = threadIdx.x;
    int v = (tid < nchunks) ? csum[tid] : 0;
    tmp[tid] = v;
    __syncthreads();
    for (int off = 1; off < 256; off <<= 1) {
        int t_ = (tid >= off) ? tmp[tid - off] : 0;
        __syncthreads();
        tmp[tid] += t_;
        __syncthreads();
    }
    if (tid < nchunks) csum[tid] = tmp[tid] - v;  // exclusive
    if (tid == 0) rowptr[n] = e;
}

__global__ __launch_bounds__(256) void k_s3(const int* __restrict__ histM,
                                            const int* __restrict__ csum,
                                            int* __restrict__ offM,
                                            int* __restrict__ bbase, int total) {
    __shared__ int tsum[256];
    const int t = threadIdx.x;
    const int base = blockIdx.x * SCH + t * 8;
    int v[8];
#pragma unroll
    for (int j = 0; j < 8; ++j) {
        int idx = base + j;
        v[j] = (idx < total) ? histM[idx] : 0;
    }
    int pre[9];
    pre[0] = 0;
#pragma unroll
    for (int j = 0; j < 8; ++j) pre[j + 1] = pre[j] + v[j];
    tsum[t] = pre[8];
    __syncthreads();
    for (int off = 1; off < 256; off <<= 1) {
        int tv = (t >= off) ? tsum[t - off] : 0;
        __syncthreads();
        tsum[t] += tv;
        __syncthreads();
    }
    const int b0 = csum[blockIdx.x] + (tsum[t] - pre[8]);
#pragma unroll
    for (int j = 0; j < 8; ++j) {
        int idx = base + j;
        if (idx < total) {
            int val = b0 + pre[j];
            offM[idx] = val;
            if ((idx & (NBLK - 1)) == 0) bbase[idx >> NBLKSH] = val;
        }
    }
}

// ================= pass 3: scatter via LDS cursors (no global atomics) =================
// packed: src | (local_dst << 20)   (src < 2^20, local_dst < 128)

__global__ __launch_bounds__(256) void k_bscatter2(const int* __restrict__ src,
                                                   const int* __restrict__ dst,
                                                   const int* __restrict__ offM,
                                                   int* __restrict__ ebuf, int e, int nb) {
    __shared__ int lcur[NBMAX];
    const int t = threadIdx.x;
    const int blk = blockIdx.x;
    for (int i = t; i < nb; i += 256) lcur[i] = offM[i * NBLK + blk];
    __syncthreads();
    const int chunk = (e + NBLK - 1) / NBLK;
    const int beg = blk * chunk, end = min(beg + chunk, e);
    for (int i = beg + t; i < end; i += 256) {
        int s = src[i], d = dst[i];
        int b = d >> BSH;
        int p = atomicAdd(&lcur[b], 1);  // LDS atomic: block-local contention only
        ebuf[p] = s | ((d & (BSZ - 1)) << 20);
    }
}

// ================= per-bucket counting sort -> CSR (+rowptr, dinv) =================

__global__ __launch_bounds__(256) void k_bsort(const int* __restrict__ ebuf,
                                               const int* __restrict__ bbase,
                                               int* __restrict__ esrc,
                                               int* __restrict__ rowptr,
                                               float* __restrict__ dinv,
                                               int n, int nb, int e) {
    __shared__ int hist[BSZ];
    __shared__ int sc[BSZ];
    __shared__ int hoff[BSZ];
    const int t = threadIdx.x;
    const int b = blockIdx.x;
    const int node0 = b << BSH;
    if (t < BSZ) hist[t] = 0;
    __syncthreads();
    const int beg = bbase[b];
    const int end = (b + 1 < nb) ? bbase[b + 1] : e;
    for (int i = beg + t; i < end; i += 256)
        atomicAdd(&hist[ebuf[i] >> 20], 1);
    __syncthreads();
    int v = (t < BSZ) ? hist[t] : 0;
    if (t < BSZ) sc[t] = v;
    __syncthreads();
    for (int off = 1; off < BSZ; off <<= 1) {
        int add = (t < BSZ && t >= off) ? sc[t - off] : 0;
        __syncthreads();
        if (t < BSZ) sc[t] += add;
        __syncthreads();
    }
    if (t < BSZ) {
        int excl = sc[t] - v;
        hoff[t] = excl;  // cursor
        int node = node0 + t;
        if (node < n) {
            rowptr[node] = beg + excl;
            dinv[node] = rsqrtf((float)(v + 1));  // +1 self loop; always > 0
        }
    }
    __syncthreads();
    for (int i = beg + t; i < end; i += 256) {
        int pk = ebuf[i];
        int dloc = pk >> 20;
        int p = beg + atomicAdd(&hoff[dloc], 1);
        esrc[p] = pk & 0xFFFFF;
    }
}

// ================= GEMM1: P1 = (x @ W1) * dinv[row]  [N,128]x[128,64] =================

__global__ __launch_bounds__(256) void k_gemm1(const float* __restrict__ x,
                                               const float* __restrict__ W,
                                               const float* __restrict__ dinv,
                                               float* __restrict__ P, int n) {
    __shared__ float Ws[IN_DIM * HID];  // 32 KB
    const int t = threadIdx.x;
    {
        const float4* W4 = (const float4*)W;
        float4* Ws4 = (float4*)Ws;
#pragma unroll
        for (int i = 0; i < 8; ++i) Ws4[t + 256 * i] = W4[t + 256 * i];
    }
    __syncthreads();

    const int row0 = blockIdx.x * 64;
    const int ty = t >> 4, tx = t & 15;  // 4 rows x 4 cols per thread
    float acc[4][4];
#pragma unroll
    for (int i = 0; i < 4; ++i)
#pragma unroll
        for (int j = 0; j < 4; ++j) acc[i][j] = 0.f;

    const float4* x4 = (const float4*)x;
    int gr[4];
#pragma unroll
    for (int i = 0; i < 4; ++i) {
        int r = row0 + ty * 4 + i;
        gr[i] = r < n ? r : (n - 1);  // clamp for safe load; store is guarded
    }

#pragma unroll 2
    for (int k = 0; k < IN_DIM; k += 4) {
        float aa[4][4];
#pragma unroll
        for (int i = 0; i < 4; ++i) {
            float4 av = x4[(size_t)gr[i] * 32 + (k >> 2)];
            aa[i][0] = av.x; aa[i][1] = av.y; aa[i][2] = av.z; aa[i][3] = av.w;
        }
#pragma unroll
        for (int q = 0; q < 4; ++q) {
            float4 bv = *(const float4*)&Ws[(k + q) * HID + tx * 4];
#pragma unroll
            for (int i = 0; i < 4; ++i) {
                acc[i][0] = fmaf(aa[i][q], bv.x, acc[i][0]);
                acc[i][1] = fmaf(aa[i][q], bv.y, acc[i][1]);
                acc[i][2] = fmaf(aa[i][q], bv.z, acc[i][2]);
                acc[i][3] = fmaf(aa[i][q], bv.w, acc[i][3]);
            }
        }
    }

#pragma unroll
    for (int i = 0; i < 4; ++i) {
        int r = row0 + ty * 4 + i;
        if (r < n) {
            float s = dinv[r];
            float4 o = make_float4(acc[i][0] * s, acc[i][1] * s, acc[i][2] * s, acc[i][3] * s);
            *(float4*)&P[(size_t)r * HID + tx * 4] = o;
        }
    }
}

// ========== fused layer1 aggregation + GEMM2: P2 = (relu-agg h) @ W2 * dinv ==========
// One 64-lane wave per node (4 nodes/block). After the xor-combine each lane holds the
// full h-fragment for its q; grp0 stages the h-row in LDS; after a block barrier,
// 160 threads compute P2[node][c] directly (W2 reads are L1-resident, 10 KB).
// Removes the k_gemm2 dispatch and the 25.6 MB h buffer entirely.

__global__ __launch_bounds__(256) void k_agg1f(const int* __restrict__ rowptr,
                                               const int* __restrict__ esrc,
                                               const float4* __restrict__ P4,
                                               const float* __restrict__ dinv,
                                               const float* __restrict__ b1,
                                               const float* __restrict__ W2,
                                               float* __restrict__ P2, int n) {
    __shared__ float hrow[4][HID];  // 1 KB
    const int t = threadIdx.x;
    const int lane = t & 63;
    const int w = t >> 6;
    const int node0 = blockIdx.x * 4;
    int node = node0 + w;
    const int nodec = node < n ? node : (n - 1);  // clamp: loads safe, stores guarded
    const int grp = lane >> 4, q = lane & 15;     // 16 float4 = 64 feats
    const int beg = rowptr[nodec], end = rowptr[nodec + 1];

    float4 acc = make_float4(0.f, 0.f, 0.f, 0.f);
    int j = beg;
#pragma unroll 4
    for (; j + 3 < end; j += 4) {
        int s = esrc[j + grp];
        float4 v = P4[(size_t)s * 16 + q];
        acc.x += v.x; acc.y += v.y; acc.z += v.z; acc.w += v.w;
    }
    if (j + grp < end) {
        int s = esrc[j + grp];
        float4 v = P4[(size_t)s * 16 + q];
        acc.x += v.x; acc.y += v.y; acc.z += v.z; acc.w += v.w;
    }
    // combine the 4 edge-slots: xor 16 then xor 32
    acc.x += __shfl_xor(acc.x, 16); acc.y += __shfl_xor(acc.y, 16);
    acc.z += __shfl_xor(acc.z, 16); acc.w += __shfl_xor(acc.w, 16);
    acc.x += __shfl_xor(acc.x, 32); acc.y += __shfl_xor(acc.y, 32);
    acc.z += __shfl_xor(acc.z, 32); acc.w += __shfl_xor(acc.w, 32);

    if (grp == 0) {  // h = relu(dinv*(acc+self)+b1) -> LDS
        float4 self = P4[(size_t)nodec * 16 + q];
        float di = dinv[nodec];
        float4 bb = *(const float4*)&b1[q * 4];
        float4 r;
        r.x = fmaxf(fmaf(di, acc.x + self.x, bb.x), 0.f);
        r.y = fmaxf(fmaf(di, acc.y + self.y, bb.y), 0.f);
        r.z = fmaxf(fmaf(di, acc.z + self.z, bb.z), 0.f);
        r.w = fmaxf(fmaf(di, acc.w + self.w, bb.w), 0.f);
        *(float4*)&hrow[w][q * 4] = r;
    }
    __syncthreads();

    // P2 phase: thread t -> (local node = t/40, col c = t%40), 160 active threads
    if (t < 4 * ODIM) {
        const int local = t / ODIM, c = t - local * ODIM;
        int pn = node0 + local;
        if (pn < n) {
            float s = 0.f;
#pragma unroll
            for (int k = 0; k < HID; ++k) s = fmaf(hrow[local][k], W2[k * ODIM + c], s);
            P2[(size_t)pn * ODIM + c] = s * dinv[pn];
        }
    }
}

// layer2 aggregation: 40 feats = 10 float4 per row (stride 160B, 16B aligned).
// 6 edge-slots x 10 chunks = 60 active lanes; 3-step combine lands on lanes 0..9.

__global__ __launch_bounds__(256) void k_agg2(const int* __restrict__ rowptr,
                                              const int* __restrict__ esrc,
                                              const float4* __restrict__ P4,
                                              const float* __restrict__ dinv,
                                              const float* __restrict__ b,
                                              float4* __restrict__ out4, int n) {
    const int t = threadIdx.x;
    const int lane = t & 63;
    const int node = blockIdx.x * 4 + (t >> 6);
    if (node >= n) return;
    const int grp = lane / 10;          // 0..6 (lanes 60-63: grp 6, inactive)
    const int q = lane - grp * 10;      // 0..9
    const bool act = grp < 6;
    const int beg = rowptr[node], end = rowptr[node + 1];

    float4 acc = make_float4(0.f, 0.f, 0.f, 0.f);
    int j = beg;
#pragma unroll 4
    for (; j + 5 < end; j += 6) {
        if (act) {
            int s = esrc[j + grp];
            float4 v = P4[(size_t)s * 10 + q];
            acc.x += v.x; acc.y += v.y; acc.z += v.z; acc.w += v.w;
        }
    }
    if (act && j + grp < end) {
        int s = esrc[j + grp];
        float4 v = P4[(size_t)s * 10 + q];
        acc.x += v.x; acc.y += v.y; acc.z += v.z; acc.w += v.w;
    }

    {
        float tx_ = __shfl(acc.x, lane + 30), ty_ = __shfl(acc.y, lane + 30);
        float tz_ = __shfl(acc.z, lane + 30), tw_ = __shfl(acc.w, lane + 30);
        if (lane < 30) { acc.x += tx_; acc.y += ty_; acc.z += tz_; acc.w += tw_; }
    }
    {
        float tx_ = __shfl(acc.x, lane + 20), ty_ = __shfl(acc.y, lane + 20);
        float tz_ = __shfl(acc.z, lane + 20), tw_ = __shfl(acc.w, lane + 20);
        if (lane < 10) { acc.x += tx_; acc.y += ty_; acc.z += tz_; acc.w += tw_; }
    }
    {
        float tx_ = __shfl(acc.x, lane + 10), ty_ = __shfl(acc.y, lane + 10);
        float tz_ = __shfl(acc.z, lane + 10), tw_ = __shfl(acc.w, lane + 10);
        if (lane < 10) { acc.x += tx_; acc.y += ty_; acc.z += tz_; acc.w += tw_; }
    }

    if (lane < 10) {  // full sums live here
        float4 self = P4[(size_t)node * 10 + q];
        float di = dinv[node];
        float4 bb = *(const float4*)&b[q * 4];
        float4 r;
        r.x = fmaf(di, acc.x + self.x, bb.x);
        r.y = fmaf(di, acc.y + self.y, bb.y);
        r.z = fmaf(di, acc.z + self.z, bb.z);
        r.w = fmaf(di, acc.w + self.w, bb.w);
        out4[(size_t)node * 10 + q] = r;  // 10 lanes: 160B store
    }
}

// ================= launch =================

extern "C" void kernel_launch(void* const* d_in, const int* in_sizes, int n_in,
                              void* d_out, int out_size, void* d_ws, size_t ws_size,
                              hipStream_t stream) {
    const float* x  = (const float*)d_in[0];
    const int*   ei = (const int*)d_in[1];
    const float* W1 = (const float*)d_in[2];
    const float* b1 = (const float*)d_in[3];
    const float* W2 = (const float*)d_in[4];
    const float* b2 = (const float*)d_in[5];

    const int n = in_sizes[0] / IN_DIM;   // 100000
    const int e = in_sizes[1] / 2;        // 1600000
    const int* src = ei;
    const int* dst = ei + e;
    const int nb = (n + BSZ - 1) >> BSH;  // 782
    const int total = nb * NBLK;          // ~200K
    const int nchunks = (total + SCH - 1) / SCH;  // 98

    auto align = [](size_t b) { return (b + 255) & ~(size_t)255; };
    char* ws = (char*)d_ws;
    size_t o = 0;
    int*   histM = (int*)(ws + o);   o += align((size_t)NBMAX * NBLK * 4);  // 1 MB
    int*   offM  = (int*)(ws + o);   o += align((size_t)NBMAX * NBLK * 4);  // 1 MB
    int*   csum  = (int*)(ws + o);   o += align((size_t)256 * 4);
    int*   bbase = (int*)(ws + o);   o += align((size_t)NBMAX * 4);
    float* dinv  = (float*)(ws + o); o += align((size_t)n * 4);
    int*   rowptr= (int*)(ws + o);   o += align((size_t)(n + 1) * 4);
    int*   ebuf  = (int*)(ws + o);   o += align((size_t)e * 4);             // 6.4 MB
    int*   esrc  = (int*)(ws + o);   o += align((size_t)e * 4);             // 6.4 MB
    float* P1    = (float*)(ws + o); o += align((size_t)n * HID * 4);       // 25.6 MB
    float* P2    = (float*)(ws + o); o += align((size_t)n * ODIM * 4);      // 16 MB
    // total ~58 MB; no memset needed (all buffers fully written each call)

    float* out = (float*)d_out;

    // ---- radix-partition CSR build (no global atomics, hierarchical scan) ----
    k_hist<<<NBLK, 256, 0, stream>>>(dst, histM, e, nb);
    k_s1<<<nchunks, 256, 0, stream>>>(histM, csum, total);
    k_s2<<<1, 256, 0, stream>>>(csum, nchunks, rowptr, n, e);
    k_s3<<<nchunks, 256, 0, stream>>>(histM, csum, offM, bbase, total);
    k_bscatter2<<<NBLK, 256, 0, stream>>>(src, dst, offM, ebuf, e, nb);
    k_bsort<<<nb, 256, 0, stream>>>(ebuf, bbase, esrc, rowptr, dinv, n, nb, e);

    // ---- layer 1 (GEMM) ----
    k_gemm1<<<(n + 63) / 64, 256, 0, stream>>>(x, W1, dinv, P1, n);

    // ---- fused layer-1 aggregation + layer-2 transform ----
    k_agg1f<<<(n + 3) / 4, 256, 0, stream>>>(rowptr, esrc, (const float4*)P1, dinv, b1,
                                             W2, P2, n);

    // ---- layer-2 aggregation (final output) ----
    k_agg2<<<(n + 3) / 4, 256, 0, stream>>>(rowptr, esrc, (const float4*)P2, dinv, b2,
                                            (float4*)out, n);
}